// Round 31
// baseline (152.594 us; speedup 1.0000x reference)
//
#include <hip/hip_runtime.h>
#include <cstdint>
#include <cstddef>

#define S_   2048
#define D_   2048
#define NH_  32
#define NKV_ 8
#define HD_  64

using bf16x8 = __attribute__((ext_vector_type(8))) __bf16;
using f32x4  = __attribute__((ext_vector_type(4))) float;

#define AS_GLOBAL(p) (const __attribute__((address_space(1))) void*)(p)
#define AS_LDS(p)    (__attribute__((address_space(3))) void*)(p)

__device__ __forceinline__ float b2f(uint u) {
  union { uint u; float f; } c; c.u = u << 16; return c.f;
}

// ---------------- fused f32 -> bf16 bulk convert (5 regions) --------------
// 3584 blocks x 256 threads x 4 float4 = 3,670,016 float4 exactly.
__global__ __launch_bounds__(256) void cvt_all(
    const float* __restrict__ hs, const float* __restrict__ wq,
    const float* __restrict__ wk, const float* __restrict__ wv,
    const float* __restrict__ wo,
    __bf16* __restrict__ hs_bf, __bf16* __restrict__ wq_bf,
    __bf16* __restrict__ wk_bf, __bf16* __restrict__ wv_bf,
    __bf16* __restrict__ wo_bf) {
#pragma unroll
  for (int p = 0; p < 4; ++p) {
    int i = blockIdx.x * 1024 + p * 256 + threadIdx.x;
    const float* src; __bf16* dst; int base;
    if (i < 1048576)      { src = hs; dst = hs_bf; base = 0; }
    else if (i < 2097152) { src = wq; dst = wq_bf; base = 1048576; }
    else if (i < 2359296) { src = wk; dst = wk_bf; base = 2097152; }
    else if (i < 2621440) { src = wv; dst = wv_bf; base = 2359296; }
    else                  { src = wo; dst = wo_bf; base = 2621440; }
    i -= base;
    const float4 v = reinterpret_cast<const float4*>(src)[i];
    __bf16 t[4] = {(__bf16)v.x, (__bf16)v.y, (__bf16)v.z, (__bf16)v.w};
    reinterpret_cast<uint2*>(dst)[i] = *reinterpret_cast<uint2*>(t);
  }
}

// ---------------- GEMM fragment compute (128-wide, for wo) ----------------
__device__ __forceinline__ void gemm_compute_step(
    const char* ldsA, const char* ldsB, f32x4 (&acc)[4][4],
    int l15, int lg, int wm, int wn) {
  bf16x8 af[4][2], bfr[4][2];
#pragma unroll
  for (int f = 0; f < 4; ++f) {
    const int arow = wm*64 + f*16 + l15;
    const int brow = wn*64 + f*16 + l15;
#pragma unroll
    for (int ks = 0; ks < 2; ++ks) {
      af[f][ks] = *reinterpret_cast<const bf16x8*>(
          ldsA + arow*128 + (((ks*4 + lg) ^ (arow & 7)) << 4));
      bfr[f][ks] = *reinterpret_cast<const bf16x8*>(
          ldsB + brow*128 + (((ks*4 + lg) ^ (brow & 7)) << 4));
    }
  }
#pragma unroll
  for (int mf = 0; mf < 4; ++mf)
#pragma unroll
    for (int nf = 0; nf < 4; ++nf) {
      acc[mf][nf] = __builtin_amdgcn_mfma_f32_16x16x32_bf16(
          af[mf][0], bfr[nf][0], acc[mf][nf], 0, 0, 0);
      acc[mf][nf] = __builtin_amdgcn_mfma_f32_16x16x32_bf16(
          af[mf][1], bfr[nf][1], acc[mf][nf], 0, 0, 0);
    }
}

// ---------------- qkv: 128x64 tile, 2-buffer pipeline (R30 known-good) ----
// 768 blocks = exactly 3/CU (48KB LDS each) -> no block-count quantization.
template <int MODE>
__device__ __forceinline__ void gemm_tile_64_bf(
    char (*lds)[24576],
    const __bf16* __restrict__ A, const __bf16* __restrict__ B,
    __bf16* __restrict__ C, int K, int N, int m0, int n0,
    const float* __restrict__ cosT, const float* __restrict__ sinT,
    const float* __restrict__ nw) {
  const int tid = threadIdx.x;
  const int l = tid & 63;
  const int w = tid >> 6;            // 0..3: wave's 32-row stripe
  const int l15 = l & 15, lg = l >> 4;

  f32x4 acc[2][4] = {};

  const int srow   = tid >> 3;       // 0..31
  const int schunk = (tid & 7) ^ (srow & 7);
  const __bf16* gA = A + (size_t)(m0 + srow) * K + schunk * 8;
  const __bf16* gB = B + (size_t)(n0 + srow) * K + schunk * 8;
  const int ldst = tid * 16;
  const int nt = K >> 6;

  auto stage = [&](char* buf, int k0) {
#pragma unroll
    for (int i = 0; i < 4; ++i)
      __builtin_amdgcn_global_load_lds(AS_GLOBAL(gA + (size_t)i*32*K + k0),
                                       AS_LDS(buf + i*4096 + ldst), 16, 0, 0);
#pragma unroll
    for (int i = 0; i < 2; ++i)
      __builtin_amdgcn_global_load_lds(AS_GLOBAL(gB + (size_t)i*32*K + k0),
                                       AS_LDS(buf + 16384 + i*4096 + ldst), 16, 0, 0);
  };

  stage(&lds[0][0], 0);
  __syncthreads();

  int cur = 0;
  for (int t = 0; t < nt; ++t) {
    if (t + 1 < nt) stage(&lds[cur ^ 1][0], (t + 1) * 64);

    // ---- compute 32x64 on buffer cur ----
    {
      const char* ldsA = &lds[cur][0];
      const char* ldsB = &lds[cur][16384];
      bf16x8 af[2][2], bfr[4][2];
#pragma unroll
      for (int f = 0; f < 2; ++f) {
        const int arow = w*32 + f*16 + l15;
#pragma unroll
        for (int ks = 0; ks < 2; ++ks)
          af[f][ks] = *reinterpret_cast<const bf16x8*>(
              ldsA + arow*128 + (((ks*4 + lg) ^ (arow & 7)) << 4));
      }
#pragma unroll
      for (int nf = 0; nf < 4; ++nf) {
        const int brow = nf*16 + l15;
#pragma unroll
        for (int ks = 0; ks < 2; ++ks)
          bfr[nf][ks] = *reinterpret_cast<const bf16x8*>(
              ldsB + brow*128 + (((ks*4 + lg) ^ (brow & 7)) << 4));
      }
#pragma unroll
      for (int mf = 0; mf < 2; ++mf)
#pragma unroll
        for (int nf = 0; nf < 4; ++nf) {
          acc[mf][nf] = __builtin_amdgcn_mfma_f32_16x16x32_bf16(
              af[mf][0], bfr[nf][0], acc[mf][nf], 0, 0, 0);
          acc[mf][nf] = __builtin_amdgcn_mfma_f32_16x16x32_bf16(
              af[mf][1], bfr[nf][1], acc[mf][nf], 0, 0, 0);
        }
    }
    __syncthreads();
    cur ^= 1;
  }

  if constexpr (MODE == 0) {
#pragma unroll
    for (int mf = 0; mf < 2; ++mf)
#pragma unroll
      for (int nf = 0; nf < 4; ++nf)
#pragma unroll
        for (int r = 0; r < 4; ++r)
          C[(size_t)(m0 + w*32 + mf*16 + lg*4 + r) * N + n0 + nf*16 + l15]
              = (__bf16)acc[mf][nf][r];
  } else {
    // fused RoPE + RMSNorm epilogue (block's 64-col range = one head)
    const float fin = (MODE == 1) ? 0.180336880111120426f : 1.0f;  // (1/8)*log2e
    float wv_[4];
#pragma unroll
    for (int nf = 0; nf < 4; ++nf) wv_[nf] = nw[nf*16 + l15];
    const int odd = l15 & 1;
#pragma unroll
    for (int mf = 0; mf < 2; ++mf) {
#pragma unroll
      for (int r = 0; r < 4; ++r) {
        const int row = m0 + w*32 + mf*16 + lg*4 + r;   // sequence position
        float ro[4];
        float ssq = 0.f;
#pragma unroll
        for (int nf = 0; nf < 4; ++nf) {
          const float v = acc[mf][nf][r];
          const float p = __shfl_xor(v, 1);
          const int d2 = (nf*16 + l15) >> 1;
          const float c  = cosT[row*32 + d2];
          const float sn = sinT[row*32 + d2];
          ro[nf] = odd ? fmaf(p, sn, v*c) : fmaf(v, c, -p*sn);
          ssq = fmaf(ro[nf], ro[nf], ssq);
        }
        ssq += __shfl_xor(ssq, 1);
        ssq += __shfl_xor(ssq, 2);
        ssq += __shfl_xor(ssq, 4);
        ssq += __shfl_xor(ssq, 8);
        const float rinv = rsqrtf(ssq * (1.0f/64.0f) + 1e-5f);
#pragma unroll
        for (int nf = 0; nf < 4; ++nf)
          C[(size_t)row * N + n0 + nf*16 + l15]
              = (__bf16)(ro[nf] * rinv * wv_[nf] * fin);
      }
    }
  }
}

// ---------------- bf16 MFMA GEMM, 3-buffer depth-2 counted-vmcnt ----------
// (for gemm_wo: 256 blocks = 1/CU regime where d2 pays — R13-validated)
__device__ __forceinline__ void gemm_tile_128_d2(
    const __bf16* __restrict__ A, const __bf16* __restrict__ B,
    float* __restrict__ C, int K, int N, int m0, int n0) {
  __shared__ __align__(16) char lds[3][32768];   // [buf][A 16K | B 16K]
  const int tid = threadIdx.x;
  const int l = tid & 63;
  const int w = tid >> 6;
  const int l15 = l & 15, lg = l >> 4;
  const int wm = w >> 1, wn = w & 1;

  f32x4 acc[4][4] = {};

  const int srow   = tid >> 3;
  const int schunk = (tid & 7) ^ (srow & 7);
  const __bf16* gA = A + (size_t)(m0 + srow) * K + schunk * 8;
  const __bf16* gB = B + (size_t)(n0 + srow) * K + schunk * 8;
  const int ldst = tid * 16;
  const int nt = K >> 6;

#pragma unroll
  for (int i = 0; i < 4; ++i) {
    __builtin_amdgcn_global_load_lds(AS_GLOBAL(gA + (size_t)i*32*K),
                                     AS_LDS(&lds[0][i*4096 + ldst]), 16, 0, 0);
    __builtin_amdgcn_global_load_lds(AS_GLOBAL(gB + (size_t)i*32*K),
                                     AS_LDS(&lds[0][16384 + i*4096 + ldst]), 16, 0, 0);
  }
#pragma unroll
  for (int i = 0; i < 4; ++i) {
    __builtin_amdgcn_global_load_lds(AS_GLOBAL(gA + (size_t)i*32*K + 64),
                                     AS_LDS(&lds[1][i*4096 + ldst]), 16, 0, 0);
    __builtin_amdgcn_global_load_lds(AS_GLOBAL(gB + (size_t)i*32*K + 64),
                                     AS_LDS(&lds[1][16384 + i*4096 + ldst]), 16, 0, 0);
  }

  char* p0 = &lds[0][0];   // read target
  char* p1 = &lds[1][0];   // in flight
  char* p2 = &lds[2][0];   // stage target

  for (int t = 0; t < nt; ++t) {
    if (t + 1 < nt) asm volatile("s_waitcnt vmcnt(8)" ::: "memory");
    else            asm volatile("s_waitcnt vmcnt(0)" ::: "memory");
    __builtin_amdgcn_s_barrier();   // raw: no vmcnt(0) drain

    if (t + 2 < nt) {
      const int k0 = (t + 2) * 64;
#pragma unroll
      for (int i = 0; i < 4; ++i) {
        __builtin_amdgcn_global_load_lds(AS_GLOBAL(gA + (size_t)i*32*K + k0),
                                         AS_LDS(p2 + i*4096 + ldst), 16, 0, 0);
        __builtin_amdgcn_global_load_lds(AS_GLOBAL(gB + (size_t)i*32*K + k0),
                                         AS_LDS(p2 + 16384 + i*4096 + ldst), 16, 0, 0);
      }
    }

    gemm_compute_step(p0, p0 + 16384, acc, l15, lg, wm, wn);

    char* tmp = p0; p0 = p1; p1 = p2; p2 = tmp;   // rotate buffers
  }

#pragma unroll
  for (int mf = 0; mf < 4; ++mf)
#pragma unroll
    for (int nf = 0; nf < 4; ++nf)
#pragma unroll
      for (int r = 0; r < 4; ++r)
        C[(size_t)(m0 + wm*64 + mf*16 + lg*4 + r) * N + n0 + wn*64 + nf*16 + l15]
            = acc[mf][nf][r];
}

// fused Q/K/V projection + rope/norm epilogues, 128x64 tiles:
// grid (48,16) = 768 blocks = 3/CU exactly, all blocks equal FLOPs.
// bx 0..31 -> q (MODE 1), 32..39 -> k (MODE 2), 40..47 -> v (MODE 0).
__global__ __launch_bounds__(256) void gemm_qkv(
    const __bf16* __restrict__ hs,
    const __bf16* __restrict__ wq, const __bf16* __restrict__ wk,
    const __bf16* __restrict__ wv,
    __bf16* __restrict__ qbf, __bf16* __restrict__ kbf, __bf16* __restrict__ vp,
    const float* __restrict__ fcos, const float* __restrict__ fsin,
    const float* __restrict__ qw, const float* __restrict__ kw) {
  __shared__ __align__(16) char lds[2][24576];   // 48KB -> 3 blocks/CU
  const int bx = blockIdx.x;
  const int m0 = blockIdx.y * 128;
  if (bx < 32) {
    gemm_tile_64_bf<1>(lds, hs, wq, qbf, 2048, 2048, m0, bx*64, fcos, fsin, qw);
  } else if (bx < 40) {
    gemm_tile_64_bf<2>(lds, hs, wk, kbf, 2048, 512, m0, (bx-32)*64, fcos, fsin, kw);
  } else {
    gemm_tile_64_bf<0>(lds, hs, wv, vp, 2048, 512, m0, (bx-40)*64,
                       nullptr, nullptr, nullptr);
  }
}

__global__ __launch_bounds__(256) void gemm_wo(
    const __bf16* __restrict__ ypre, const __bf16* __restrict__ wo,
    float* __restrict__ y) {
  gemm_tile_128_d2(ypre, wo, y, 2048, 2048, blockIdx.y * 128, blockIdx.x * 128);
}

// ---------------- fused transposes: khT (f32 out) + vh/vT -----------------
// grid (64, 8): x<32 -> khT path (s0 = x*64), x>=32 -> V path (s0 = (x-32)*64)
__global__ __launch_bounds__(256) void transpose_kv(
    const __bf16* __restrict__ kpost, float* __restrict__ khT,
    const __bf16* __restrict__ vp, float* __restrict__ vh,
    __bf16* __restrict__ vtbf) {
  __shared__ float tl[64][68];
  const int kvh = blockIdx.y;
  const int t = threadIdx.x;
  if (blockIdx.x < 32) {
    const int s0 = blockIdx.x * 64;
    {
      const int d0 = (t & 15) * 4;
      const int sl = t >> 4;
#pragma unroll
      for (int rep = 0; rep < 4; ++rep) {
        const int srow = sl + rep*16;
        const uint2 v = *reinterpret_cast<const uint2*>(
            &kpost[(size_t)(s0 + srow)*(NKV_*HD_) + kvh*HD_ + d0]);
        tl[d0+0][srow] = b2f(v.x & 0xffff);
        tl[d0+1][srow] = b2f(v.x >> 16);
        tl[d0+2][srow] = b2f(v.y & 0xffff);
        tl[d0+3][srow] = b2f(v.y >> 16);
      }
    }
    __syncthreads();
    {
      const int d  = t >> 2;
      const int s4 = (t & 3) * 16;
#pragma unroll
      for (int c = 0; c < 4; ++c) {
        float4 v;
        v.x = tl[d][s4+c*4+0]; v.y = tl[d][s4+c*4+1];
        v.z = tl[d][s4+c*4+2]; v.w = tl[d][s4+c*4+3];
#pragma unroll
        for (int r = 0; r < 4; ++r) {
          *reinterpret_cast<float4*>(
              &khT[((size_t)(kvh*4 + r)*HD_ + d)*S_ + s0 + s4 + c*4]) = v;
        }
      }
    }
  } else {
    const int s0 = (blockIdx.x - 32) * 64;
    const int srow = t >> 2, dc = (t & 3) * 16;
    const __bf16* src = &vp[(size_t)(s0 + srow)*(NKV_*HD_) + kvh*HD_ + dc];
    const uint4 a = reinterpret_cast<const uint4*>(src)[0];
    const uint4 b = reinterpret_cast<const uint4*>(src)[1];
    float f[16];
    f[0]=b2f(a.x&0xffff); f[1]=b2f(a.x>>16); f[2]=b2f(a.y&0xffff); f[3]=b2f(a.y>>16);
    f[4]=b2f(a.z&0xffff); f[5]=b2f(a.z>>16); f[6]=b2f(a.w&0xffff); f[7]=b2f(a.w>>16);
    f[8]=b2f(b.x&0xffff); f[9]=b2f(b.x>>16); f[10]=b2f(b.y&0xffff); f[11]=b2f(b.y>>16);
    f[12]=b2f(b.z&0xffff); f[13]=b2f(b.z>>16); f[14]=b2f(b.w&0xffff); f[15]=b2f(b.w>>16);
#pragma unroll
    for (int i = 0; i < 16; ++i) tl[srow][dc + i] = f[i];
#pragma unroll
    for (int r = 0; r < 4; ++r) {
      float* dst = &vh[((size_t)(kvh*4 + r)*S_ + s0 + srow)*HD_ + dc];
#pragma unroll
      for (int cc = 0; cc < 4; ++cc) {
        float4 v4 = {f[cc*4+0], f[cc*4+1], f[cc*4+2], f[cc*4+3]};
        reinterpret_cast<float4*>(dst)[cc] = v4;
      }
    }
    __syncthreads();
    const int dr = t >> 2, sc = (t & 3) * 16;
    __bf16 vals[16];
#pragma unroll
    for (int i = 0; i < 16; ++i) vals[i] = (__bf16)tl[sc + i][dr];
    uint4* dst = reinterpret_cast<uint4*>(&vtbf[((size_t)(kvh*64 + dr))*S_ + s0 + sc]);
    dst[0] = reinterpret_cast<uint4*>(vals)[0];
    dst[1] = reinterpret_cast<uint4*>(vals)[1];
  }
}

// ---------------- flash helpers (swapped-operand T12 form) ----------------
__device__ __forceinline__ uint pack2bf(float a, float b) {
  __bf16 x = (__bf16)a, y = (__bf16)b;
  const uint ux = (uint)*reinterpret_cast<ushort*>(&x);
  const uint uy = (uint)*reinterpret_cast<ushort*>(&y);
  return ux | (uy << 16);
}

// 3-input max (clang fuses nested fmaxf to v_max3_f32 on gfx9+)
__device__ __forceinline__ float max3f(float a, float b, float c) {
  return fmaxf(fmaxf(a, b), c);
}

// S^T = K * Q^T : lane holds S[key = nb*16+lg*4+r][qrow = wg*16 + l15]
__device__ __forceinline__ void qk_tile_T(
    const char* kldh, bf16x8 qf0, bf16x8 qf1, f32x4 (&s_)[4],
    int l15, int lg) {
  __builtin_amdgcn_s_setprio(1);
#pragma unroll
  for (int nb = 0; nb < 4; ++nb) {
    const int row = nb*16 + l15;                 // key row in kld
    const int bc  = lg*16;
    const bf16x8 kb0 = *reinterpret_cast<const bf16x8*>(
        kldh + row*128 + ((bc)      ^ ((row & 7) << 4)));
    const bf16x8 kb1 = *reinterpret_cast<const bf16x8*>(
        kldh + row*128 + ((bc + 64) ^ ((row & 7) << 4)));
    f32x4 t = f32x4{0.f, 0.f, 0.f, 0.f};
    t = __builtin_amdgcn_mfma_f32_16x16x32_bf16(kb0, qf0, t, 0, 0, 0);  // swapped
    t = __builtin_amdgcn_mfma_f32_16x16x32_bf16(kb1, qf1, t, 0, 0, 0);
    s_[nb] = t;
  }
  __builtin_amdgcn_s_setprio(0);
}

// exp2-domain softmax (lane-local rows) + T13 defer-max + swapped PV.
__device__ __forceinline__ void softmax_pv_T(
    f32x4 (&s_)[4], float& m_, float& l_, f32x4 (&o_)[4],
    char* pldw, const char* vbase, int l15, int lg) {
  // 16-value max via v_max3 tree (T17): 6 max3 + 1 fmax vs 15 pairwise
  const float a0 = max3f(s_[0][0], s_[0][1], s_[0][2]);
  const float a1 = max3f(s_[0][3], s_[1][0], s_[1][1]);
  const float a2 = max3f(s_[1][2], s_[1][3], s_[2][0]);
  const float a3 = max3f(s_[2][1], s_[2][2], s_[2][3]);
  const float a4 = max3f(s_[3][0], s_[3][1], s_[3][2]);
  const float b0 = max3f(a0, a1, a2);
  const float b1 = max3f(a3, a4, s_[3][3]);
  float mx = fmaxf(b0, b1);
  mx = fmaxf(mx, __shfl_xor(mx, 16));
  mx = fmaxf(mx, __shfl_xor(mx, 32));

  // T13 defer-max: skip rescale when all rows stay within 2^8 of running max
  if (!__all(mx <= m_ + 8.f)) {
    const float mnew = fmaxf(m_, mx);
    const float scl = exp2f(m_ - mnew);
    m_ = mnew;
    l_ *= scl;
#pragma unroll
    for (int nb = 0; nb < 4; ++nb) {
      o_[nb][0] *= scl; o_[nb][1] *= scl; o_[nb][2] *= scl; o_[nb][3] *= scl;
    }
  }

  const int swz = (l15 & 7) << 4;
  float ls = 0.f;
#pragma unroll
  for (int nb = 0; nb < 4; ++nb) {
    float p0 = exp2f(s_[nb][0] - m_);
    float p1 = exp2f(s_[nb][1] - m_);
    float p2 = exp2f(s_[nb][2] - m_);
    float p3 = exp2f(s_[nb][3] - m_);
    ls += (p0 + p1) + (p2 + p3);
    // merged 8B store: offsets X and X+4 share the same 16B swizzle chunk
    uint2 pw;
    pw.x = pack2bf(p0, p1);
    pw.y = pack2bf(p2, p3);
    *reinterpret_cast<uint2*>(pldw + ((l15*128 + nb*32 + lg*8) ^ swz)) = pw;
  }
  ls += __shfl_xor(ls, 16);
  ls += __shfl_xor(ls, 32);
  l_ += ls;

  const bf16x8 pb0 = *reinterpret_cast<const bf16x8*>(
      pldw + ((l15*128 + lg*16)      ^ swz));
  const bf16x8 pb1 = *reinterpret_cast<const bf16x8*>(
      pldw + ((l15*128 + lg*16 + 64) ^ swz));

  __builtin_amdgcn_s_setprio(1);
#pragma unroll
  for (int nb = 0; nb < 4; ++nb) {
    const int row = nb*16 + l15;                 // d row in vtl
    const int bc  = lg*16;
    const bf16x8 v0 = *reinterpret_cast<const bf16x8*>(
        vbase + row*128 + ((bc)      ^ ((row & 7) << 4)));
    const bf16x8 v1 = *reinterpret_cast<const bf16x8*>(
        vbase + row*128 + ((bc + 64) ^ ((row & 7) << 4)));
    f32x4 t = o_[nb];
    t = __builtin_amdgcn_mfma_f32_16x16x32_bf16(v0, pb0, t, 0, 0, 0);  // O^T
    t = __builtin_amdgcn_mfma_f32_16x16x32_bf16(v1, pb1, t, 0, 0, 0);
    o_[nb] = t;
  }
  __builtin_amdgcn_s_setprio(0);
}

// causal mask in S^T layout: key = nb*16+lg*4+r, qrow = wg*16 + l15
__device__ __forceinline__ void mask_diag_T(f32x4 (&s_)[4], int l15, int lg, int wg) {
  const int qrow = wg*16 + l15;
#pragma unroll
  for (int nb = 0; nb < 4; ++nb)
#pragma unroll
    for (int r = 0; r < 4; ++r)
      if (nb*16 + lg*4 + r > qrow) s_[nb][r] = -1e30f;
}

// ---------------- causal flash attention, paired q-tiles, kt-parity split -
// R31: ILP reorder — both QK^T tiles (independent MFMA) issue BEFORE the
// two softmax+PV phases, so qkA's MFMAs overlap smB's VALU chain.
__global__ __launch_bounds__(512, 4) void flash_attn_mfma(
    const __bf16* __restrict__ qbf, const __bf16* __restrict__ kbf,
    const __bf16* __restrict__ vtbf, __bf16* __restrict__ ypre) {
  __shared__ __align__(16) char smem[49152];

  const int h   = blockIdx.y;
  const int pi  = blockIdx.x;       // 0..15
  const int qbA = pi, qbB = 31 - pi;
  const int SS  = (qbB >> 1) + 1;   // super-steps (2 kts each)
  const int kvh = h >> 2;
  const int tid = threadIdx.x;
  const int l   = tid & 63;
  const int w   = tid >> 6;         // 0..7
  const int g   = tid >> 8;         // kt parity group
  const int wg  = w & 3;            // row-group within q-tile
  const int l15 = l & 15;
  const int lg  = l >> 4;

  char* kldg = smem + g*8192;
  char* vtlg = smem + 16384 + g*8192;
  char* pldw = smem + 32768 + w*2048;

  const int ts = tid & 255;
  const int j  = ts >> 2;
  const int c0 = (ts & 3) * 16;
  const int b0 = (j*128 + c0*2)      ^ ((j & 7) << 4);
  const int b1 = (j*128 + c0*2 + 16) ^ ((j & 7) << 4);
  const __bf16* ksrc = kbf  + (size_t)(g*64 + j)*(NKV_*HD_) + kvh*HD_ + c0;
  const __bf16* vsrc = vtbf + (size_t)(kvh*64 + j)*S_ + g*64 + c0;

  bf16x8 qfA0, qfA1, qfB0, qfB1;
  {
    const __bf16* qa = qbf + (size_t)(qbA*64 + wg*16 + l15)*D_ + h*HD_ + lg*8;
    qfA0 = *reinterpret_cast<const bf16x8*>(qa);
    qfA1 = *reinterpret_cast<const bf16x8*>(qa + 32);
    const __bf16* qb = qbf + (size_t)(qbB*64 + wg*16 + l15)*D_ + h*HD_ + lg*8;
    qfB0 = *reinterpret_cast<const bf16x8*>(qb);
    qfB1 = *reinterpret_cast<const bf16x8*>(qb + 32);
  }

  f32x4 oA[4], oB[4];
#pragma unroll
  for (int nb = 0; nb < 4; ++nb) {
    oA[nb] = f32x4{0.f, 0.f, 0.f, 0.f};
    oB[nb] = f32x4{0.f, 0.f, 0.f, 0.f};
  }
  float mA = -1e30f, lA = 0.f, mB = -1e30f, lB = 0.f;

  uint4 kr0 = reinterpret_cast<const uint4*>(ksrc)[0];
  uint4 kr1 = reinterpret_cast<const uint4*>(ksrc + 8)[0];
  uint4 vr0 = reinterpret_cast<const uint4*>(vsrc)[0];
  uint4 vr1 = reinterpret_cast<const uint4*>(vsrc + 8)[0];

  for (int st = 0; st < SS; ++st) {
    __syncthreads();
    *reinterpret_cast<uint4*>(kldg + b0) = kr0;
    *reinterpret_cast<uint4*>(kldg + b1) = kr1;
    *reinterpret_cast<uint4*>(vtlg + b0) = vr0;
    *reinterpret_cast<uint4*>(vtlg + b1) = vr1;
    __syncthreads();

    if (st + 1 < SS) {
      const __bf16* kn = ksrc + (size_t)(st + 1)*128*(NKV_*HD_);
      const __bf16* vn = vsrc + (size_t)(st + 1)*128;
      kr0 = reinterpret_cast<const uint4*>(kn)[0];
      kr1 = reinterpret_cast<const uint4*>(kn + 8)[0];
      vr0 = reinterpret_cast<const uint4*>(vn)[0];
      vr1 = reinterpret_cast<const uint4*>(vn + 8)[0];
    }

    const int kt = 2*st + g;
    const bool doB = (kt <= qbB);
    const bool doA = (kt <= qbA);
    f32x4 sB[4], sA[4];
    // both QK^T tiles first: independent MFMA clusters feed the pipe
    // while the softmax VALU chains run below.
    if (doB) {
      qk_tile_T(kldg, qfB0, qfB1, sB, l15, lg);
      if (kt == qbB) mask_diag_T(sB, l15, lg, wg);
    }
    if (doA) {
      qk_tile_T(kldg, qfA0, qfA1, sA, l15, lg);
      if (kt == qbA) mask_diag_T(sA, l15, lg, wg);
    }
    if (doB) softmax_pv_T(sB, mB, lB, oB, pldw, vtlg, l15, lg);
    if (doA) softmax_pv_T(sA, mA, lA, oA, pldw, vtlg, l15, lg);
  }

  // ---- merge parities (group1 -> LDS, group0 combines) ----
  float* ox = reinterpret_cast<float*>(smem);                 // 256 lanes x 17
  float* ml = reinterpret_cast<float*>(smem + 20480);         // 256 lanes x 9
  float* po = ox + (wg*64 + l)*17;
  float* pm = ml + (wg*64 + l)*9;

  __syncthreads();
  if (g == 1) {
#pragma unroll
    for (int nb = 0; nb < 4; ++nb)
#pragma unroll
      for (int r = 0; r < 4; ++r) po[nb*4 + r] = oB[nb][r];
    pm[0] = mB; pm[1] = lB;
  }
  __syncthreads();
  if (g == 0) {
    const float m1 = pm[0], l1 = pm[1];
    const float m = fmaxf(mB, m1);
    const float s0 = exp2f(mB - m), s1 = exp2f(m1 - m);
    lB = lB*s0 + l1*s1;
#pragma unroll
    for (int nb = 0; nb < 4; ++nb)
#pragma unroll
      for (int r = 0; r < 4; ++r)
        oB[nb][r] = oB[nb][r]*s0 + po[nb*4 + r]*s1;
  }
  __syncthreads();
  if (g == 1) {
#pragma unroll
    for (int nb = 0; nb < 4; ++nb)
#pragma unroll
      for (int r = 0; r < 4; ++r) po[nb*4 + r] = oA[nb][r];
    pm[0] = mA; pm[1] = lA;
  }
  __syncthreads();
  if (g == 0) {
    const float m1 = pm[0], l1 = pm[1];
    const float m = fmaxf(mA, m1);
    const float s0 = exp2f(mA - m), s1 = exp2f(m1 - m);
    lA = lA*s0 + l1*s1;
#pragma unroll
    for (int nb = 0; nb < 4; ++nb)
#pragma unroll
      for (int r = 0; r < 4; ++r)
        oA[nb][r] = oA[nb][r]*s0 + po[nb*4 + r]*s1;

    const float rlA = 1.0f / lA, rlB = 1.0f / lB;
    const size_t rowA = (size_t)(qbA*64 + wg*16 + l15)*D_ + h*HD_;
    const size_t rowB = (size_t)(qbB*64 + wg*16 + l15)*D_ + h*HD_;
#pragma unroll
    for (int nb = 0; nb < 4; ++nb) {
      uint2 pa, pb;
      pa.x = pack2bf(oA[nb][0]*rlA, oA[nb][1]*rlA);
      pa.y = pack2bf(oA[nb][2]*rlA, oA[nb][3]*rlA);
      pb.x = pack2bf(oB[nb][0]*rlB, oB[nb][1]*rlB);
      pb.y = pack2bf(oB[nb][2]*rlB, oB[nb][3]*rlB);
      *reinterpret_cast<uint2*>(&ypre[rowA + nb*16 + lg*4]) = pa;
      *reinterpret_cast<uint2*>(&ypre[rowB + nb*16 + lg*4]) = pb;
    }
  }
}

// --------------------------------------------------------------------------
extern "C" void kernel_launch(void* const* d_in, const int* in_sizes, int n_in,
                              void* d_out, int out_size, void* d_ws, size_t ws_size,
                              hipStream_t stream) {
  (void)in_sizes; (void)n_in; (void)out_size;
  const float* hs   = (const float*)d_in[0];
  const float* fcos = (const float*)d_in[1];
  const float* fsin = (const float*)d_in[2];
  const float* wq = (const float*)d_in[4];
  const float* wk = (const float*)d_in[5];
  const float* wv = (const float*)d_in[6];
  const float* wo = (const float*)d_in[7];
  const float* qw = (const float*)d_in[8];
  const float* kw = (const float*)d_in[9];

  float* out = (float*)d_out;
  float* y   = out;                 // 2048*2048
  float* khT = out + 4194304;       // 32*64*2048
  float* vh  = out + 8388608;       // 32*2048*64

  __bf16* qbf   = (__bf16*)y;
  __bf16* kbf   = (__bf16*)((char*)y + 8*1024*1024);
  __bf16* vtbf  = (__bf16*)((char*)y + 10*1024*1024);
  __bf16* hs_bf = (__bf16*)khT;
  __bf16* wq_bf = (__bf16*)((char*)khT + 8*1024*1024);
  __bf16* wk_bf = (__bf16*)vh;
  __bf16* wv_bf = (__bf16*)((char*)vh + 2*1024*1024);

  const size_t need = (size_t)40 * 1024 * 1024;
  if (ws_size < need) return;
  char* ws = (char*)d_ws;
  __bf16* vp_bf   = (__bf16*)(ws);                   // 2MB
  __bf16* ypre_bf = (__bf16*)(ws + 2*1024*1024);     // 8MB
  __bf16* wo_bf   = (__bf16*)(ws + 10*1024*1024);    // 8MB

  cvt_all<<<3584, 256, 0, stream>>>(hs, wq, wk, wv, wo,
                                    hs_bf, wq_bf, wk_bf, wv_bf, wo_bf);

  // qkv GEMM: 128x64 tiles, 768 blocks = 3/CU exactly (no quantization)
  gemm_qkv<<<dim3(48, 16), 256, 0, stream>>>(hs_bf, wq_bf, wk_bf, wv_bf,
                                             qbf, kbf, vp_bf,
                                             fcos, fsin, qw, kw);

  transpose_kv<<<dim3(64, 8), 256, 0, stream>>>(kbf, khT, vp_bf, vh, vtbf);

  flash_attn_mfma<<<dim3(16, 32), 512, 0, stream>>>(qbf, kbf, vtbf, ypre_bf);

  gemm_wo<<<dim3(16, 16), 256, 0, stream>>>(ypre_bf, wo_bf, y);
}

// Round 32
// 132.827 us; speedup vs baseline: 1.1488x; 1.1488x over previous
//
#include <hip/hip_runtime.h>
#include <cstdint>
#include <cstddef>

#define S_   2048
#define D_   2048
#define NH_  32
#define NKV_ 8
#define HD_  64

using bf16x8 = __attribute__((ext_vector_type(8))) __bf16;
using f32x4  = __attribute__((ext_vector_type(4))) float;

#define AS_GLOBAL(p) (const __attribute__((address_space(1))) void*)(p)
#define AS_LDS(p)    (__attribute__((address_space(3))) void*)(p)

__device__ __forceinline__ float b2f(uint u) {
  union { uint u; float f; } c; c.u = u << 16; return c.f;
}

// ---------------- fused f32 -> bf16 bulk convert (5 regions) --------------
// 3584 blocks x 256 threads x 4 float4 = 3,670,016 float4 exactly.
__global__ __launch_bounds__(256) void cvt_all(
    const float* __restrict__ hs, const float* __restrict__ wq,
    const float* __restrict__ wk, const float* __restrict__ wv,
    const float* __restrict__ wo,
    __bf16* __restrict__ hs_bf, __bf16* __restrict__ wq_bf,
    __bf16* __restrict__ wk_bf, __bf16* __restrict__ wv_bf,
    __bf16* __restrict__ wo_bf) {
#pragma unroll
  for (int p = 0; p < 4; ++p) {
    int i = blockIdx.x * 1024 + p * 256 + threadIdx.x;
    const float* src; __bf16* dst; int base;
    if (i < 1048576)      { src = hs; dst = hs_bf; base = 0; }
    else if (i < 2097152) { src = wq; dst = wq_bf; base = 1048576; }
    else if (i < 2359296) { src = wk; dst = wk_bf; base = 2097152; }
    else if (i < 2621440) { src = wv; dst = wv_bf; base = 2359296; }
    else                  { src = wo; dst = wo_bf; base = 2621440; }
    i -= base;
    const float4 v = reinterpret_cast<const float4*>(src)[i];
    __bf16 t[4] = {(__bf16)v.x, (__bf16)v.y, (__bf16)v.z, (__bf16)v.w};
    reinterpret_cast<uint2*>(dst)[i] = *reinterpret_cast<uint2*>(t);
  }
}

// ---------------- GEMM fragment compute (128-wide, for wo) ----------------
__device__ __forceinline__ void gemm_compute_step(
    const char* ldsA, const char* ldsB, f32x4 (&acc)[4][4],
    int l15, int lg, int wm, int wn) {
  bf16x8 af[4][2], bfr[4][2];
#pragma unroll
  for (int f = 0; f < 4; ++f) {
    const int arow = wm*64 + f*16 + l15;
    const int brow = wn*64 + f*16 + l15;
#pragma unroll
    for (int ks = 0; ks < 2; ++ks) {
      af[f][ks] = *reinterpret_cast<const bf16x8*>(
          ldsA + arow*128 + (((ks*4 + lg) ^ (arow & 7)) << 4));
      bfr[f][ks] = *reinterpret_cast<const bf16x8*>(
          ldsB + brow*128 + (((ks*4 + lg) ^ (brow & 7)) << 4));
    }
  }
#pragma unroll
  for (int mf = 0; mf < 4; ++mf)
#pragma unroll
    for (int nf = 0; nf < 4; ++nf) {
      acc[mf][nf] = __builtin_amdgcn_mfma_f32_16x16x32_bf16(
          af[mf][0], bfr[nf][0], acc[mf][nf], 0, 0, 0);
      acc[mf][nf] = __builtin_amdgcn_mfma_f32_16x16x32_bf16(
          af[mf][1], bfr[nf][1], acc[mf][nf], 0, 0, 0);
    }
}

// ---------------- qkv: 128x64 tile, 2-buffer pipeline (R30 known-good) ----
// 768 blocks = exactly 3/CU (48KB LDS each) -> no block-count quantization.
template <int MODE>
__device__ __forceinline__ void gemm_tile_64_bf(
    char (*lds)[24576],
    const __bf16* __restrict__ A, const __bf16* __restrict__ B,
    __bf16* __restrict__ C, int K, int N, int m0, int n0,
    const float* __restrict__ cosT, const float* __restrict__ sinT,
    const float* __restrict__ nw) {
  const int tid = threadIdx.x;
  const int l = tid & 63;
  const int w = tid >> 6;            // 0..3: wave's 32-row stripe
  const int l15 = l & 15, lg = l >> 4;

  f32x4 acc[2][4] = {};

  const int srow   = tid >> 3;       // 0..31
  const int schunk = (tid & 7) ^ (srow & 7);
  const __bf16* gA = A + (size_t)(m0 + srow) * K + schunk * 8;
  const __bf16* gB = B + (size_t)(n0 + srow) * K + schunk * 8;
  const int ldst = tid * 16;
  const int nt = K >> 6;

  auto stage = [&](char* buf, int k0) {
#pragma unroll
    for (int i = 0; i < 4; ++i)
      __builtin_amdgcn_global_load_lds(AS_GLOBAL(gA + (size_t)i*32*K + k0),
                                       AS_LDS(buf + i*4096 + ldst), 16, 0, 0);
#pragma unroll
    for (int i = 0; i < 2; ++i)
      __builtin_amdgcn_global_load_lds(AS_GLOBAL(gB + (size_t)i*32*K + k0),
                                       AS_LDS(buf + 16384 + i*4096 + ldst), 16, 0, 0);
  };

  stage(&lds[0][0], 0);
  __syncthreads();

  int cur = 0;
  for (int t = 0; t < nt; ++t) {
    if (t + 1 < nt) stage(&lds[cur ^ 1][0], (t + 1) * 64);

    // ---- compute 32x64 on buffer cur ----
    {
      const char* ldsA = &lds[cur][0];
      const char* ldsB = &lds[cur][16384];
      bf16x8 af[2][2], bfr[4][2];
#pragma unroll
      for (int f = 0; f < 2; ++f) {
        const int arow = w*32 + f*16 + l15;
#pragma unroll
        for (int ks = 0; ks < 2; ++ks)
          af[f][ks] = *reinterpret_cast<const bf16x8*>(
              ldsA + arow*128 + (((ks*4 + lg) ^ (arow & 7)) << 4));
      }
#pragma unroll
      for (int nf = 0; nf < 4; ++nf) {
        const int brow = nf*16 + l15;
#pragma unroll
        for (int ks = 0; ks < 2; ++ks)
          bfr[nf][ks] = *reinterpret_cast<const bf16x8*>(
              ldsB + brow*128 + (((ks*4 + lg) ^ (brow & 7)) << 4));
      }
#pragma unroll
      for (int mf = 0; mf < 2; ++mf)
#pragma unroll
        for (int nf = 0; nf < 4; ++nf) {
          acc[mf][nf] = __builtin_amdgcn_mfma_f32_16x16x32_bf16(
              af[mf][0], bfr[nf][0], acc[mf][nf], 0, 0, 0);
          acc[mf][nf] = __builtin_amdgcn_mfma_f32_16x16x32_bf16(
              af[mf][1], bfr[nf][1], acc[mf][nf], 0, 0, 0);
        }
    }
    __syncthreads();
    cur ^= 1;
  }

  if constexpr (MODE == 0) {
#pragma unroll
    for (int mf = 0; mf < 2; ++mf)
#pragma unroll
      for (int nf = 0; nf < 4; ++nf)
#pragma unroll
        for (int r = 0; r < 4; ++r)
          C[(size_t)(m0 + w*32 + mf*16 + lg*4 + r) * N + n0 + nf*16 + l15]
              = (__bf16)acc[mf][nf][r];
  } else {
    // fused RoPE + RMSNorm epilogue (block's 64-col range = one head)
    const float fin = (MODE == 1) ? 0.180336880111120426f : 1.0f;  // (1/8)*log2e
    float wv_[4];
#pragma unroll
    for (int nf = 0; nf < 4; ++nf) wv_[nf] = nw[nf*16 + l15];
    const int odd = l15 & 1;
#pragma unroll
    for (int mf = 0; mf < 2; ++mf) {
#pragma unroll
      for (int r = 0; r < 4; ++r) {
        const int row = m0 + w*32 + mf*16 + lg*4 + r;   // sequence position
        float ro[4];
        float ssq = 0.f;
#pragma unroll
        for (int nf = 0; nf < 4; ++nf) {
          const float v = acc[mf][nf][r];
          const float p = __shfl_xor(v, 1);
          const int d2 = (nf*16 + l15) >> 1;
          const float c  = cosT[row*32 + d2];
          const float sn = sinT[row*32 + d2];
          ro[nf] = odd ? fmaf(p, sn, v*c) : fmaf(v, c, -p*sn);
          ssq = fmaf(ro[nf], ro[nf], ssq);
        }
        ssq += __shfl_xor(ssq, 1);
        ssq += __shfl_xor(ssq, 2);
        ssq += __shfl_xor(ssq, 4);
        ssq += __shfl_xor(ssq, 8);
        const float rinv = rsqrtf(ssq * (1.0f/64.0f) + 1e-5f);
#pragma unroll
        for (int nf = 0; nf < 4; ++nf)
          C[(size_t)row * N + n0 + nf*16 + l15]
              = (__bf16)(ro[nf] * rinv * wv_[nf] * fin);
      }
    }
  }
}

// ---------------- bf16 MFMA GEMM, 3-buffer depth-2 counted-vmcnt ----------
// (for gemm_wo: 256 blocks = 1/CU regime where d2 pays — R13-validated)
__device__ __forceinline__ void gemm_tile_128_d2(
    const __bf16* __restrict__ A, const __bf16* __restrict__ B,
    float* __restrict__ C, int K, int N, int m0, int n0) {
  __shared__ __align__(16) char lds[3][32768];   // [buf][A 16K | B 16K]
  const int tid = threadIdx.x;
  const int l = tid & 63;
  const int w = tid >> 6;
  const int l15 = l & 15, lg = l >> 4;
  const int wm = w >> 1, wn = w & 1;

  f32x4 acc[4][4] = {};

  const int srow   = tid >> 3;
  const int schunk = (tid & 7) ^ (srow & 7);
  const __bf16* gA = A + (size_t)(m0 + srow) * K + schunk * 8;
  const __bf16* gB = B + (size_t)(n0 + srow) * K + schunk * 8;
  const int ldst = tid * 16;
  const int nt = K >> 6;

#pragma unroll
  for (int i = 0; i < 4; ++i) {
    __builtin_amdgcn_global_load_lds(AS_GLOBAL(gA + (size_t)i*32*K),
                                     AS_LDS(&lds[0][i*4096 + ldst]), 16, 0, 0);
    __builtin_amdgcn_global_load_lds(AS_GLOBAL(gB + (size_t)i*32*K),
                                     AS_LDS(&lds[0][16384 + i*4096 + ldst]), 16, 0, 0);
  }
#pragma unroll
  for (int i = 0; i < 4; ++i) {
    __builtin_amdgcn_global_load_lds(AS_GLOBAL(gA + (size_t)i*32*K + 64),
                                     AS_LDS(&lds[1][i*4096 + ldst]), 16, 0, 0);
    __builtin_amdgcn_global_load_lds(AS_GLOBAL(gB + (size_t)i*32*K + 64),
                                     AS_LDS(&lds[1][16384 + i*4096 + ldst]), 16, 0, 0);
  }

  char* p0 = &lds[0][0];   // read target
  char* p1 = &lds[1][0];   // in flight
  char* p2 = &lds[2][0];   // stage target

  for (int t = 0; t < nt; ++t) {
    if (t + 1 < nt) asm volatile("s_waitcnt vmcnt(8)" ::: "memory");
    else            asm volatile("s_waitcnt vmcnt(0)" ::: "memory");
    __builtin_amdgcn_s_barrier();   // raw: no vmcnt(0) drain

    if (t + 2 < nt) {
      const int k0 = (t + 2) * 64;
#pragma unroll
      for (int i = 0; i < 4; ++i) {
        __builtin_amdgcn_global_load_lds(AS_GLOBAL(gA + (size_t)i*32*K + k0),
                                         AS_LDS(p2 + i*4096 + ldst), 16, 0, 0);
        __builtin_amdgcn_global_load_lds(AS_GLOBAL(gB + (size_t)i*32*K + k0),
                                         AS_LDS(p2 + 16384 + i*4096 + ldst), 16, 0, 0);
      }
    }

    gemm_compute_step(p0, p0 + 16384, acc, l15, lg, wm, wn);

    char* tmp = p0; p0 = p1; p1 = p2; p2 = tmp;   // rotate buffers
  }

#pragma unroll
  for (int mf = 0; mf < 4; ++mf)
#pragma unroll
    for (int nf = 0; nf < 4; ++nf)
#pragma unroll
      for (int r = 0; r < 4; ++r)
        C[(size_t)(m0 + wm*64 + mf*16 + lg*4 + r) * N + n0 + wn*64 + nf*16 + l15]
            = acc[mf][nf][r];
}

// fused Q/K/V projection + rope/norm epilogues, 128x64 tiles:
// grid (48,16) = 768 blocks = 3/CU exactly, all blocks equal FLOPs.
// bx 0..31 -> q (MODE 1), 32..39 -> k (MODE 2), 40..47 -> v (MODE 0).
__global__ __launch_bounds__(256) void gemm_qkv(
    const __bf16* __restrict__ hs,
    const __bf16* __restrict__ wq, const __bf16* __restrict__ wk,
    const __bf16* __restrict__ wv,
    __bf16* __restrict__ qbf, __bf16* __restrict__ kbf, __bf16* __restrict__ vp,
    const float* __restrict__ fcos, const float* __restrict__ fsin,
    const float* __restrict__ qw, const float* __restrict__ kw) {
  __shared__ __align__(16) char lds[2][24576];   // 48KB -> 3 blocks/CU
  const int bx = blockIdx.x;
  const int m0 = blockIdx.y * 128;
  if (bx < 32) {
    gemm_tile_64_bf<1>(lds, hs, wq, qbf, 2048, 2048, m0, bx*64, fcos, fsin, qw);
  } else if (bx < 40) {
    gemm_tile_64_bf<2>(lds, hs, wk, kbf, 2048, 512, m0, (bx-32)*64, fcos, fsin, kw);
  } else {
    gemm_tile_64_bf<0>(lds, hs, wv, vp, 2048, 512, m0, (bx-40)*64,
                       nullptr, nullptr, nullptr);
  }
}

__global__ __launch_bounds__(256) void gemm_wo(
    const __bf16* __restrict__ ypre, const __bf16* __restrict__ wo,
    float* __restrict__ y) {
  gemm_tile_128_d2(ypre, wo, y, 2048, 2048, blockIdx.y * 128, blockIdx.x * 128);
}

// ---------------- fused transposes: khT (f32 out) + vh/vT -----------------
// grid (64, 8): x<32 -> khT path (s0 = x*64), x>=32 -> V path (s0 = (x-32)*64)
__global__ __launch_bounds__(256) void transpose_kv(
    const __bf16* __restrict__ kpost, float* __restrict__ khT,
    const __bf16* __restrict__ vp, float* __restrict__ vh,
    __bf16* __restrict__ vtbf) {
  __shared__ float tl[64][68];
  const int kvh = blockIdx.y;
  const int t = threadIdx.x;
  if (blockIdx.x < 32) {
    const int s0 = blockIdx.x * 64;
    {
      const int d0 = (t & 15) * 4;
      const int sl = t >> 4;
#pragma unroll
      for (int rep = 0; rep < 4; ++rep) {
        const int srow = sl + rep*16;
        const uint2 v = *reinterpret_cast<const uint2*>(
            &kpost[(size_t)(s0 + srow)*(NKV_*HD_) + kvh*HD_ + d0]);
        tl[d0+0][srow] = b2f(v.x & 0xffff);
        tl[d0+1][srow] = b2f(v.x >> 16);
        tl[d0+2][srow] = b2f(v.y & 0xffff);
        tl[d0+3][srow] = b2f(v.y >> 16);
      }
    }
    __syncthreads();
    {
      const int d  = t >> 2;
      const int s4 = (t & 3) * 16;
#pragma unroll
      for (int c = 0; c < 4; ++c) {
        float4 v;
        v.x = tl[d][s4+c*4+0]; v.y = tl[d][s4+c*4+1];
        v.z = tl[d][s4+c*4+2]; v.w = tl[d][s4+c*4+3];
#pragma unroll
        for (int r = 0; r < 4; ++r) {
          *reinterpret_cast<float4*>(
              &khT[((size_t)(kvh*4 + r)*HD_ + d)*S_ + s0 + s4 + c*4]) = v;
        }
      }
    }
  } else {
    const int s0 = (blockIdx.x - 32) * 64;
    const int srow = t >> 2, dc = (t & 3) * 16;
    const __bf16* src = &vp[(size_t)(s0 + srow)*(NKV_*HD_) + kvh*HD_ + dc];
    const uint4 a = reinterpret_cast<const uint4*>(src)[0];
    const uint4 b = reinterpret_cast<const uint4*>(src)[1];
    float f[16];
    f[0]=b2f(a.x&0xffff); f[1]=b2f(a.x>>16); f[2]=b2f(a.y&0xffff); f[3]=b2f(a.y>>16);
    f[4]=b2f(a.z&0xffff); f[5]=b2f(a.z>>16); f[6]=b2f(a.w&0xffff); f[7]=b2f(a.w>>16);
    f[8]=b2f(b.x&0xffff); f[9]=b2f(b.x>>16); f[10]=b2f(b.y&0xffff); f[11]=b2f(b.y>>16);
    f[12]=b2f(b.z&0xffff); f[13]=b2f(b.z>>16); f[14]=b2f(b.w&0xffff); f[15]=b2f(b.w>>16);
#pragma unroll
    for (int i = 0; i < 16; ++i) tl[srow][dc + i] = f[i];
#pragma unroll
    for (int r = 0; r < 4; ++r) {
      float* dst = &vh[((size_t)(kvh*4 + r)*S_ + s0 + srow)*HD_ + dc];
#pragma unroll
      for (int cc = 0; cc < 4; ++cc) {
        float4 v4 = {f[cc*4+0], f[cc*4+1], f[cc*4+2], f[cc*4+3]};
        reinterpret_cast<float4*>(dst)[cc] = v4;
      }
    }
    __syncthreads();
    const int dr = t >> 2, sc = (t & 3) * 16;
    __bf16 vals[16];
#pragma unroll
    for (int i = 0; i < 16; ++i) vals[i] = (__bf16)tl[sc + i][dr];
    uint4* dst = reinterpret_cast<uint4*>(&vtbf[((size_t)(kvh*64 + dr))*S_ + s0 + sc]);
    dst[0] = reinterpret_cast<uint4*>(vals)[0];
    dst[1] = reinterpret_cast<uint4*>(vals)[1];
  }
}

// ---------------- flash helpers (swapped-operand T12 form) ----------------
__device__ __forceinline__ uint pack2bf(float a, float b) {
  __bf16 x = (__bf16)a, y = (__bf16)b;
  const uint ux = (uint)*reinterpret_cast<ushort*>(&x);
  const uint uy = (uint)*reinterpret_cast<ushort*>(&y);
  return ux | (uy << 16);
}

// 3-input max (clang fuses nested fmaxf to v_max3_f32 on gfx9+)
__device__ __forceinline__ float max3f(float a, float b, float c) {
  return fmaxf(fmaxf(a, b), c);
}

// S^T = K * Q^T : lane holds S[key = nb*16+lg*4+r][qrow = wg*16 + l15]
__device__ __forceinline__ void qk_tile_T(
    const char* kldh, bf16x8 qf0, bf16x8 qf1, f32x4 (&s_)[4],
    int l15, int lg) {
  __builtin_amdgcn_s_setprio(1);
#pragma unroll
  for (int nb = 0; nb < 4; ++nb) {
    const int row = nb*16 + l15;                 // key row in kld
    const int bc  = lg*16;
    const bf16x8 kb0 = *reinterpret_cast<const bf16x8*>(
        kldh + row*128 + ((bc)      ^ ((row & 7) << 4)));
    const bf16x8 kb1 = *reinterpret_cast<const bf16x8*>(
        kldh + row*128 + ((bc + 64) ^ ((row & 7) << 4)));
    f32x4 t = f32x4{0.f, 0.f, 0.f, 0.f};
    t = __builtin_amdgcn_mfma_f32_16x16x32_bf16(kb0, qf0, t, 0, 0, 0);  // swapped
    t = __builtin_amdgcn_mfma_f32_16x16x32_bf16(kb1, qf1, t, 0, 0, 0);
    s_[nb] = t;
  }
  __builtin_amdgcn_s_setprio(0);
}

// exp2-domain softmax (lane-local rows) + T13 defer-max + swapped PV.
__device__ __forceinline__ void softmax_pv_T(
    f32x4 (&s_)[4], float& m_, float& l_, f32x4 (&o_)[4],
    char* pldw, const char* vbase, int l15, int lg) {
  // 16-value max via v_max3 tree (T17): 6 max3 + 1 fmax vs 15 pairwise
  const float a0 = max3f(s_[0][0], s_[0][1], s_[0][2]);
  const float a1 = max3f(s_[0][3], s_[1][0], s_[1][1]);
  const float a2 = max3f(s_[1][2], s_[1][3], s_[2][0]);
  const float a3 = max3f(s_[2][1], s_[2][2], s_[2][3]);
  const float a4 = max3f(s_[3][0], s_[3][1], s_[3][2]);
  const float b0 = max3f(a0, a1, a2);
  const float b1 = max3f(a3, a4, s_[3][3]);
  float mx = fmaxf(b0, b1);
  mx = fmaxf(mx, __shfl_xor(mx, 16));
  mx = fmaxf(mx, __shfl_xor(mx, 32));

  // T13 defer-max: skip rescale when all rows stay within 2^8 of running max
  if (!__all(mx <= m_ + 8.f)) {
    const float mnew = fmaxf(m_, mx);
    const float scl = exp2f(m_ - mnew);
    m_ = mnew;
    l_ *= scl;
#pragma unroll
    for (int nb = 0; nb < 4; ++nb) {
      o_[nb][0] *= scl; o_[nb][1] *= scl; o_[nb][2] *= scl; o_[nb][3] *= scl;
    }
  }

  const int swz = (l15 & 7) << 4;
  float ls = 0.f;
#pragma unroll
  for (int nb = 0; nb < 4; ++nb) {
    float p0 = exp2f(s_[nb][0] - m_);
    float p1 = exp2f(s_[nb][1] - m_);
    float p2 = exp2f(s_[nb][2] - m_);
    float p3 = exp2f(s_[nb][3] - m_);
    ls += (p0 + p1) + (p2 + p3);
    // merged 8B store: offsets X and X+4 share the same 16B swizzle chunk
    uint2 pw;
    pw.x = pack2bf(p0, p1);
    pw.y = pack2bf(p2, p3);
    *reinterpret_cast<uint2*>(pldw + ((l15*128 + nb*32 + lg*8) ^ swz)) = pw;
  }
  ls += __shfl_xor(ls, 16);
  ls += __shfl_xor(ls, 32);
  l_ += ls;

  const bf16x8 pb0 = *reinterpret_cast<const bf16x8*>(
      pldw + ((l15*128 + lg*16)      ^ swz));
  const bf16x8 pb1 = *reinterpret_cast<const bf16x8*>(
      pldw + ((l15*128 + lg*16 + 64) ^ swz));

  __builtin_amdgcn_s_setprio(1);
#pragma unroll
  for (int nb = 0; nb < 4; ++nb) {
    const int row = nb*16 + l15;                 // d row in vtl
    const int bc  = lg*16;
    const bf16x8 v0 = *reinterpret_cast<const bf16x8*>(
        vbase + row*128 + ((bc)      ^ ((row & 7) << 4)));
    const bf16x8 v1 = *reinterpret_cast<const bf16x8*>(
        vbase + row*128 + ((bc + 64) ^ ((row & 7) << 4)));
    f32x4 t = o_[nb];
    t = __builtin_amdgcn_mfma_f32_16x16x32_bf16(v0, pb0, t, 0, 0, 0);  // O^T
    t = __builtin_amdgcn_mfma_f32_16x16x32_bf16(v1, pb1, t, 0, 0, 0);
    o_[nb] = t;
  }
  __builtin_amdgcn_s_setprio(0);
}

// causal mask in S^T layout: key = nb*16+lg*4+r, qrow = wg*16 + l15
__device__ __forceinline__ void mask_diag_T(f32x4 (&s_)[4], int l15, int lg, int wg) {
  const int qrow = wg*16 + l15;
#pragma unroll
  for (int nb = 0; nb < 4; ++nb)
#pragma unroll
    for (int r = 0; r < 4; ++r)
      if (nb*16 + lg*4 + r > qrow) s_[nb][r] = -1e30f;
}

// ---------------- causal flash attention, paired q-tiles, kt-parity split -
__global__ __launch_bounds__(512, 4) void flash_attn_mfma(
    const __bf16* __restrict__ qbf, const __bf16* __restrict__ kbf,
    const __bf16* __restrict__ vtbf, __bf16* __restrict__ ypre) {
  __shared__ __align__(16) char smem[49152];

  const int h   = blockIdx.y;
  const int pi  = blockIdx.x;       // 0..15
  const int qbA = pi, qbB = 31 - pi;
  const int SS  = (qbB >> 1) + 1;   // super-steps (2 kts each)
  const int kvh = h >> 2;
  const int tid = threadIdx.x;
  const int l   = tid & 63;
  const int w   = tid >> 6;         // 0..7
  const int g   = tid >> 8;         // kt parity group
  const int wg  = w & 3;            // row-group within q-tile
  const int l15 = l & 15;
  const int lg  = l >> 4;

  char* kldg = smem + g*8192;
  char* vtlg = smem + 16384 + g*8192;
  char* pldw = smem + 32768 + w*2048;

  const int ts = tid & 255;
  const int j  = ts >> 2;
  const int c0 = (ts & 3) * 16;
  const int b0 = (j*128 + c0*2)      ^ ((j & 7) << 4);
  const int b1 = (j*128 + c0*2 + 16) ^ ((j & 7) << 4);
  const __bf16* ksrc = kbf  + (size_t)(g*64 + j)*(NKV_*HD_) + kvh*HD_ + c0;
  const __bf16* vsrc = vtbf + (size_t)(kvh*64 + j)*S_ + g*64 + c0;

  bf16x8 qfA0, qfA1, qfB0, qfB1;
  {
    const __bf16* qa = qbf + (size_t)(qbA*64 + wg*16 + l15)*D_ + h*HD_ + lg*8;
    qfA0 = *reinterpret_cast<const bf16x8*>(qa);
    qfA1 = *reinterpret_cast<const bf16x8*>(qa + 32);
    const __bf16* qb = qbf + (size_t)(qbB*64 + wg*16 + l15)*D_ + h*HD_ + lg*8;
    qfB0 = *reinterpret_cast<const bf16x8*>(qb);
    qfB1 = *reinterpret_cast<const bf16x8*>(qb + 32);
  }

  f32x4 oA[4], oB[4];
#pragma unroll
  for (int nb = 0; nb < 4; ++nb) {
    oA[nb] = f32x4{0.f, 0.f, 0.f, 0.f};
    oB[nb] = f32x4{0.f, 0.f, 0.f, 0.f};
  }
  float mA = -1e30f, lA = 0.f, mB = -1e30f, lB = 0.f;

  uint4 kr0 = reinterpret_cast<const uint4*>(ksrc)[0];
  uint4 kr1 = reinterpret_cast<const uint4*>(ksrc + 8)[0];
  uint4 vr0 = reinterpret_cast<const uint4*>(vsrc)[0];
  uint4 vr1 = reinterpret_cast<const uint4*>(vsrc + 8)[0];

  for (int st = 0; st < SS; ++st) {
    __syncthreads();
    *reinterpret_cast<uint4*>(kldg + b0) = kr0;
    *reinterpret_cast<uint4*>(kldg + b1) = kr1;
    *reinterpret_cast<uint4*>(vtlg + b0) = vr0;
    *reinterpret_cast<uint4*>(vtlg + b1) = vr1;
    __syncthreads();

    if (st + 1 < SS) {
      const __bf16* kn = ksrc + (size_t)(st + 1)*128*(NKV_*HD_);
      const __bf16* vn = vsrc + (size_t)(st + 1)*128;
      kr0 = reinterpret_cast<const uint4*>(kn)[0];
      kr1 = reinterpret_cast<const uint4*>(kn + 8)[0];
      vr0 = reinterpret_cast<const uint4*>(vn)[0];
      vr1 = reinterpret_cast<const uint4*>(vn + 8)[0];
    }

    const int kt = 2*st + g;
    if (kt <= qbB) {
      f32x4 s_[4];
      qk_tile_T(kldg, qfB0, qfB1, s_, l15, lg);
      if (kt == qbB) mask_diag_T(s_, l15, lg, wg);
      softmax_pv_T(s_, mB, lB, oB, pldw, vtlg, l15, lg);
    }
    if (kt <= qbA) {
      f32x4 s_[4];
      qk_tile_T(kldg, qfA0, qfA1, s_, l15, lg);
      if (kt == qbA) mask_diag_T(s_, l15, lg, wg);
      softmax_pv_T(s_, mA, lA, oA, pldw, vtlg, l15, lg);
    }
  }

  // ---- merge parities (group1 -> LDS, group0 combines) ----
  float* ox = reinterpret_cast<float*>(smem);                 // 256 lanes x 17
  float* ml = reinterpret_cast<float*>(smem + 20480);         // 256 lanes x 9
  float* po = ox + (wg*64 + l)*17;
  float* pm = ml + (wg*64 + l)*9;

  __syncthreads();
  if (g == 1) {
#pragma unroll
    for (int nb = 0; nb < 4; ++nb)
#pragma unroll
      for (int r = 0; r < 4; ++r) po[nb*4 + r] = oB[nb][r];
    pm[0] = mB; pm[1] = lB;
  }
  __syncthreads();
  if (g == 0) {
    const float m1 = pm[0], l1 = pm[1];
    const float m = fmaxf(mB, m1);
    const float s0 = exp2f(mB - m), s1 = exp2f(m1 - m);
    lB = lB*s0 + l1*s1;
#pragma unroll
    for (int nb = 0; nb < 4; ++nb)
#pragma unroll
      for (int r = 0; r < 4; ++r)
        oB[nb][r] = oB[nb][r]*s0 + po[nb*4 + r]*s1;
  }
  __syncthreads();
  if (g == 1) {
#pragma unroll
    for (int nb = 0; nb < 4; ++nb)
#pragma unroll
      for (int r = 0; r < 4; ++r) po[nb*4 + r] = oA[nb][r];
    pm[0] = mA; pm[1] = lA;
  }
  __syncthreads();
  if (g == 0) {
    const float m1 = pm[0], l1 = pm[1];
    const float m = fmaxf(mA, m1);
    const float s0 = exp2f(mA - m), s1 = exp2f(m1 - m);
    lA = lA*s0 + l1*s1;
#pragma unroll
    for (int nb = 0; nb < 4; ++nb)
#pragma unroll
      for (int r = 0; r < 4; ++r)
        oA[nb][r] = oA[nb][r]*s0 + po[nb*4 + r]*s1;

    const float rlA = 1.0f / lA, rlB = 1.0f / lB;
    const size_t rowA = (size_t)(qbA*64 + wg*16 + l15)*D_ + h*HD_;
    const size_t rowB = (size_t)(qbB*64 + wg*16 + l15)*D_ + h*HD_;
#pragma unroll
    for (int nb = 0; nb < 4; ++nb) {
      uint2 pa, pb;
      pa.x = pack2bf(oA[nb][0]*rlA, oA[nb][1]*rlA);
      pa.y = pack2bf(oA[nb][2]*rlA, oA[nb][3]*rlA);
      pb.x = pack2bf(oB[nb][0]*rlB, oB[nb][1]*rlB);
      pb.y = pack2bf(oB[nb][2]*rlB, oB[nb][3]*rlB);
      *reinterpret_cast<uint2*>(&ypre[rowA + nb*16 + lg*4]) = pa;
      *reinterpret_cast<uint2*>(&ypre[rowB + nb*16 + lg*4]) = pb;
    }
  }
}

// --------------------------------------------------------------------------
extern "C" void kernel_launch(void* const* d_in, const int* in_sizes, int n_in,
                              void* d_out, int out_size, void* d_ws, size_t ws_size,
                              hipStream_t stream) {
  (void)in_sizes; (void)n_in; (void)out_size;
  const float* hs   = (const float*)d_in[0];
  const float* fcos = (const float*)d_in[1];
  const float* fsin = (const float*)d_in[2];
  const float* wq = (const float*)d_in[4];
  const float* wk = (const float*)d_in[5];
  const float* wv = (const float*)d_in[6];
  const float* wo = (const float*)d_in[7];
  const float* qw = (const float*)d_in[8];
  const float* kw = (const float*)d_in[9];

  float* out = (float*)d_out;
  float* y   = out;                 // 2048*2048
  float* khT = out + 4194304;       // 32*64*2048
  float* vh  = out + 8388608;       // 32*2048*64

  __bf16* qbf   = (__bf16*)y;
  __bf16* kbf   = (__bf16*)((char*)y + 8*1024*1024);
  __bf16* vtbf  = (__bf16*)((char*)y + 10*1024*1024);
  __bf16* hs_bf = (__bf16*)khT;
  __bf16* wq_bf = (__bf16*)((char*)khT + 8*1024*1024);
  __bf16* wk_bf = (__bf16*)vh;
  __bf16* wv_bf = (__bf16*)((char*)vh + 2*1024*1024);

  const size_t need = (size_t)40 * 1024 * 1024;
  if (ws_size < need) return;
  char* ws = (char*)d_ws;
  __bf16* vp_bf   = (__bf16*)(ws);                   // 2MB
  __bf16* ypre_bf = (__bf16*)(ws + 2*1024*1024);     // 8MB
  __bf16* wo_bf   = (__bf16*)(ws + 10*1024*1024);    // 8MB

  cvt_all<<<3584, 256, 0, stream>>>(hs, wq, wk, wv, wo,
                                    hs_bf, wq_bf, wk_bf, wv_bf, wo_bf);

  // qkv GEMM: 128x64 tiles, 768 blocks = 3/CU exactly (no quantization)
  gemm_qkv<<<dim3(48, 16), 256, 0, stream>>>(hs_bf, wq_bf, wk_bf, wv_bf,
                                             qbf, kbf, vp_bf,
                                             fcos, fsin, qw, kw);

  transpose_kv<<<dim3(64, 8), 256, 0, stream>>>(kbf, khT, vp_bf, vh, vtbf);

  flash_attn_mfma<<<dim3(16, 32), 512, 0, stream>>>(qbf, kbf, vtbf, ypre_bf);

  gemm_wo<<<dim3(16, 16), 256, 0, stream>>>(ypre_bf, wo_bf, y);
}